// Round 14
// baseline (658.220 us; speedup 1.0000x reference)
//
#include <hip/hip_runtime.h>
#include <hip/hip_fp16.h>

// Hetero-GNN: 5 layers of relu(segsum_temp(x)@Wt + segmean_inter(x)@Wi + x@Wr + b)
// (aggregation commuted past the matmuls).
//
// R23 = R22 + channel-halved (L2-resident) hidden gather.
//  - R22 counters: k_gather32 FETCH=116 MB/dispatch for a 6.4 MB h16 table:
//    table > 4 MB per-XCD L2 -> ~half the random 64B row reads miss L2.
//  - Each gather now runs as TWO dispatches; half h touches only bytes
//    [32h,32h+32) of every row -> per-dispatch footprint 3.2 MB, fits every
//    XCD's L2 (launch boundary guarantees temporal separation). Lane slice
//    8B->4B (global_load_dword, one __half2), float2 accumulators; node
//    mapping / shfl / masks identical to the verified R19 kernel.
//  - Cost: csr_i/rs/cnt_t walked twice per layer (~13 MB, L3-backed) + 4
//    extra launches.

#define VO 8192        // overflow list capacity (pairs), temp relation
#define FCAP 10240     // staged edges per bucket in k_fill3 (40 KB LDS)
#define SCAT_THR 512
#define SCAT_SPAN 8192 // edges per scatter block (32 KB LDS stage)

typedef float vf4 __attribute__((ext_vector_type(4)));
typedef float vf2 __attribute__((ext_vector_type(2)));

__device__ inline void f4add(float4& a, const float4& v) {
    a.x += v.x; a.y += v.y; a.z += v.z; a.w += v.w;
}

__device__ inline float2 cvt4(float w) {
    union { float f; __half2 h; } u;
    u.f = w;
    return __half22float2(u.h);
}

// ---------------- build: hist -> scan -> scatter -> dense fill ----------------

__global__ void k_hist(const int* __restrict__ dst, int E, int* __restrict__ gh,
                       int NB, int shift) {
    __shared__ int sh[1024];
    for (int j = threadIdx.x; j < NB; j += blockDim.x) sh[j] = 0;
    __syncthreads();
    for (int i = blockIdx.x * blockDim.x + threadIdx.x; i < E; i += gridDim.x * blockDim.x)
        atomicAdd(&sh[dst[i] >> shift], 1);
    __syncthreads();
    for (int j = threadIdx.x; j < NB; j += blockDim.x)
        if (sh[j]) atomicAdd(&gh[j], sh[j]);
}

__global__ void k_scan_b(const int* __restrict__ gh, int NB, int* __restrict__ boff,
                         int* __restrict__ cur) {
    __shared__ int sh[1024];
    int t = threadIdx.x;
    sh[t] = (t < NB) ? gh[t] : 0;
    __syncthreads();
    for (int off = 1; off < 1024; off <<= 1) {
        int v = (t >= off) ? sh[t - off] : 0;
        __syncthreads();
        sh[t] += v;
        __syncthreads();
    }
    if (t < NB) {
        int ex = t ? sh[t - 1] : 0;
        boff[t] = ex;
        cur[t] = ex;
    }
    if (t == 0) boff[NB] = sh[NB - 1];
}

// write-combined scatter: count -> scan -> chunk alloc -> rank into LDS stage
// (bucket-major) -> group-per-bucket burst copy-out.
__global__ __launch_bounds__(512) void k_scatter(const int* __restrict__ src,
                                                 const int* __restrict__ dst, int E,
                                                 int shift, int NB, int* __restrict__ cur,
                                                 int* __restrict__ ebuf) {
    __shared__ int lh[1024];     // per-bucket counts
    __shared__ int lb[1024];     // per-bucket global base (chunk alloc)
    __shared__ int lstart[1024]; // per-bucket LDS stage start (exclusive scan)
    __shared__ int lcur[1024];   // ranking cursors
    __shared__ int wsum[8];
    __shared__ int stage[SCAT_SPAN];
    const int t = threadIdx.x;
    const int lane = t & 63;
    const int wv = t >> 6;
    int lo = blockIdx.x * SCAT_SPAN;
    int hi = min(E, lo + SCAT_SPAN);
    for (int j = t; j < 1024; j += 512) lh[j] = 0;
    __syncthreads();
    // pass A: count
    for (int e = lo + t; e < hi; e += 512)
        atomicAdd(&lh[dst[e] >> shift], 1);
    __syncthreads();
    // exclusive scan of lh[0..1023] -> lstart (2 elems/thread, wave shfl scan)
    int a0 = lh[2 * t], a1 = lh[2 * t + 1];
    int ts = a0 + a1;
    int run = ts;
#pragma unroll
    for (int off = 1; off < 64; off <<= 1) {
        int v = __shfl_up(run, off, 64);
        if (lane >= off) run += v;
    }
    if (lane == 63) wsum[wv] = run;
    __syncthreads();
    int wpre = 0;
#pragma unroll
    for (int w = 0; w < 8; ++w) wpre += (w < wv) ? wsum[w] : 0;
    int excl = wpre + run - ts;
    lstart[2 * t] = excl;
    lstart[2 * t + 1] = excl + a0;
    lcur[2 * t] = excl;
    lcur[2 * t + 1] = excl + a0;
    // global chunk alloc (contiguous per bucket via cur[] cursors)
    for (int j = t; j < NB; j += 512) {
        int c = lh[j];
        lb[j] = c ? atomicAdd(&cur[j], c) : 0;
    }
    __syncthreads();
    // pass B: re-read + rank into bucket-major LDS stage
    const int mask = (1 << shift) - 1;
    for (int e = lo + t; e < hi; e += 512) {
        int s = src[e];
        int d = dst[e];
        int p = atomicAdd(&lcur[d >> shift], 1);
        stage[p] = (s << shift) | (d & mask);
    }
    __syncthreads();
    // copy-out: 8 lane-groups of 8 per wave; each group streams one bucket's
    // contiguous run -> ~13 sweeps instead of 98, 4x lane utilization.
    const int grp = lane >> 3;
    const int gl = lane & 7;
    const int gid = wv * 8 + grp;     // 0..63
    for (int j = gid; j < NB; j += 64) {
        int c = lh[j];
        int sb = lstart[j];
        int gb = lb[j];
        for (int i = gl; i < c; i += 8)
            ebuf[gb + i] = stage[sb + i];
    }
}

// dense CSR fill: one block per 128-node bucket. Two streaming passes over the
// bucket's packed ebuf segment; LDS staging -> coalesced full-line csr writes.
__global__ __launch_bounds__(256) void k_fill3(const int* __restrict__ ebuf,
                                               const int* __restrict__ boff, int NB,
                                               int* __restrict__ rs, int* __restrict__ csr,
                                               int N) {
    __shared__ int hist[128];
    __shared__ int offs[129];
    __shared__ int curl[128];
    __shared__ int scn[128];
    __shared__ int stage[FCAP];
    int b = blockIdx.x;
    if (b >= NB) return;
    int lo = boff[b], hi = boff[b + 1];
    int cnt = hi - lo;
    int base = b << 7;
    int t = threadIdx.x;
    for (int i = t; i < 128; i += 256) { hist[i] = 0; curl[i] = 0; }
    __syncthreads();
    // pass 1: count
    for (int e = lo + t; e < hi; e += 256) {
        int v = ebuf[e];
        atomicAdd(&hist[v & 127], 1);
    }
    __syncthreads();
    // parallel exclusive scan of hist -> offs (Hillis-Steele over 128)
    if (t < 128) scn[t] = hist[t];
    __syncthreads();
    for (int off = 1; off < 128; off <<= 1) {
        int v = (t >= off && t < 128) ? scn[t - off] : 0;
        __syncthreads();
        if (t < 128) scn[t] += v;
        __syncthreads();
    }
    if (t < 128) offs[t] = scn[t] - hist[t];
    if (t == 0) offs[128] = scn[127];
    __syncthreads();
    // rs offsets (exact; dst < N so nodes >= N have count 0)
    for (int i = t; i < 128; i += 256) {
        int g = base + i;
        if (g < N) rs[g] = lo + offs[i];
    }
    if (b == NB - 1 && t == 0) rs[N] = hi;
    // pass 2: place
    bool staged = (cnt <= FCAP);
    for (int e = lo + t; e < hi; e += 256) {
        int v = ebuf[e];
        int dl = v & 127;
        int sidx = (int)(((unsigned)v) >> 7);
        int p = offs[dl] + atomicAdd(&curl[dl], 1);
        if (staged) stage[p] = sidx;
        else csr[lo + p] = sidx;
    }
    __syncthreads();
    if (staged)
        for (int i = t; i < cnt; i += 256) csr[lo + i] = stage[i];
}

// temp relation (100k edges): padded one-pass fill
__global__ void k_fill2(const int* __restrict__ src, const int* __restrict__ dst, int E,
                        int* __restrict__ cnt, int* __restrict__ csr, int C,
                        int* __restrict__ ovf, int* __restrict__ ovf_n) {
    int i = blockIdx.x * blockDim.x + threadIdx.x;
    if (i >= E) return;
    int s = src[i];
    int d = dst[i];
    int slot = atomicAdd(&cnt[d], 1);
    if (slot < C) {
        csr[(size_t)d * C + slot] = s;
    } else {
        int p = atomicAdd(ovf_n, 1);
        if (p < VO) { ovf[2 * p] = d; ovf[2 * p + 1] = s; }
    }
}

__global__ void k_pad_x(const float* __restrict__ x, float* __restrict__ x8, int N) {
    int i = blockIdx.x * blockDim.x + threadIdx.x;
    if (i >= N * 8) return;
    int n = i >> 3, c = i & 7;
    x8[i] = (c < 6) ? x[n * 6 + c] : 0.0f;
}

// ---------------- gathers ----------------

// group gather, 4-byte lane slice: 8 edges per batch from idxv (lane q of
// group holds edge base+q index), 8 dword loads in flight, ONE vmcnt(0).
// xq points at the lane's 2-channel slice of the CURRENT HALF.
__device__ inline void gat8d(const __half* __restrict__ xq, int idxv, int g8,
                             int base, int cnt, float2& acc) {
    int s[8];
#pragma unroll
    for (int j = 0; j < 8; ++j) s[j] = __shfl(idxv, g8 + j, 64);
    const __half* a0 = xq + (size_t)s[0] * 32;
    const __half* a1 = xq + (size_t)s[1] * 32;
    const __half* a2 = xq + (size_t)s[2] * 32;
    const __half* a3 = xq + (size_t)s[3] * 32;
    const __half* a4 = xq + (size_t)s[4] * 32;
    const __half* a5 = xq + (size_t)s[5] * 32;
    const __half* a6 = xq + (size_t)s[6] * 32;
    const __half* a7 = xq + (size_t)s[7] * 32;
    float w0, w1, w2, w3, w4, w5, w6, w7;
    asm volatile(
        "global_load_dword %0, %8, off\n\t"
        "global_load_dword %1, %9, off\n\t"
        "global_load_dword %2, %10, off\n\t"
        "global_load_dword %3, %11, off\n\t"
        "global_load_dword %4, %12, off\n\t"
        "global_load_dword %5, %13, off\n\t"
        "global_load_dword %6, %14, off\n\t"
        "global_load_dword %7, %15, off\n\t"
        "s_waitcnt vmcnt(0)"
        : "=&v"(w0), "=&v"(w1), "=&v"(w2), "=&v"(w3),
          "=&v"(w4), "=&v"(w5), "=&v"(w6), "=&v"(w7)
        : "v"(a0), "v"(a1), "v"(a2), "v"(a3), "v"(a4), "v"(a5), "v"(a6), "v"(a7)
        : "memory");
    float2 v0 = cvt4(w0), v1 = cvt4(w1), v2 = cvt4(w2), v3 = cvt4(w3);
    float2 v4 = cvt4(w4), v5 = cvt4(w5), v6 = cvt4(w6), v7 = cvt4(w7);
    if (base + 8 <= cnt) {
        acc.x += (v0.x + v1.x) + (v2.x + v3.x) + (v4.x + v5.x) + (v6.x + v7.x);
        acc.y += (v0.y + v1.y) + (v2.y + v3.y) + (v4.y + v5.y) + (v6.y + v7.y);
    } else {
        float2 vv[8] = {v0, v1, v2, v3, v4, v5, v6, v7};
#pragma unroll
        for (int j = 0; j < 8; ++j) {
            float m = (base + j < cnt) ? 1.0f : 0.0f;
            acc.x = fmaf(m, vv[j].x, acc.x);
            acc.y = fmaf(m, vv[j].y, acc.y);
        }
    }
}

// head gather, THREAD-per-node: lane owns full 8-ch fp32 row accumulators.
// Contiguous CSR segment walked in batches of 4 (4 idx + 8 float4 loads).
__global__ __launch_bounds__(256) void k_gather_head(
    const float* __restrict__ x8, const int* __restrict__ csr_i, const int* __restrict__ rs,
    const int* __restrict__ csr_t, const int* __restrict__ cnt_t, int Ct,
    const int* __restrict__ ovf_t, const int* __restrict__ ovfn,
    float* __restrict__ agg8, int N) {
    int n = blockIdx.x * blockDim.x + threadIdx.x;
    if (n >= N) return;
    int e0 = rs[n], e1 = rs[n + 1];
    int cif = e1 - e0;
    int ctf = cnt_t[n], ct = min(ctf, Ct);
    float4 ai0 = make_float4(0.f, 0.f, 0.f, 0.f), ai1 = ai0;
    for (int base = 0; base < cif; base += 4) {
        int sj[4];
#pragma unroll
        for (int j = 0; j < 4; ++j) sj[j] = csr_i[e0 + min(base + j, cif - 1)];
        float4 lo[4], hi[4];
#pragma unroll
        for (int j = 0; j < 4; ++j) {
            const float4* row = (const float4*)(x8 + (size_t)sj[j] * 8);
            lo[j] = row[0];
            hi[j] = row[1];
        }
#pragma unroll
        for (int j = 0; j < 4; ++j) {
            float m = (base + j < cif) ? 1.0f : 0.0f;
            ai0.x = fmaf(m, lo[j].x, ai0.x);
            ai0.y = fmaf(m, lo[j].y, ai0.y);
            ai0.z = fmaf(m, lo[j].z, ai0.z);
            ai0.w = fmaf(m, lo[j].w, ai0.w);
            ai1.x = fmaf(m, hi[j].x, ai1.x);
            ai1.y = fmaf(m, hi[j].y, ai1.y);
            ai1.z = fmaf(m, hi[j].z, ai1.z);
            ai1.w = fmaf(m, hi[j].w, ai1.w);
        }
    }
    float4 at0 = make_float4(0.f, 0.f, 0.f, 0.f), at1 = at0;
    for (int base = 0; base < ct; base += 4) {
        int sj[4];
#pragma unroll
        for (int j = 0; j < 4; ++j) sj[j] = csr_t[(size_t)n * Ct + min(base + j, ct - 1)];
        float4 lo[4], hi[4];
#pragma unroll
        for (int j = 0; j < 4; ++j) {
            const float4* row = (const float4*)(x8 + (size_t)sj[j] * 8);
            lo[j] = row[0];
            hi[j] = row[1];
        }
#pragma unroll
        for (int j = 0; j < 4; ++j) {
            float m = (base + j < ct) ? 1.0f : 0.0f;
            at0.x = fmaf(m, lo[j].x, at0.x);
            at0.y = fmaf(m, lo[j].y, at0.y);
            at0.z = fmaf(m, lo[j].z, at0.z);
            at0.w = fmaf(m, lo[j].w, at0.w);
            at1.x = fmaf(m, hi[j].x, at1.x);
            at1.y = fmaf(m, hi[j].y, at1.y);
            at1.z = fmaf(m, hi[j].z, at1.z);
            at1.w = fmaf(m, hi[j].w, at1.w);
        }
    }
    if (ctf > Ct) {
        int no = min(ovfn[1], VO);
        for (int j = 0; j < no; ++j) {
            int d = ovf_t[2 * j];
            if (d == n) {
                const float4* row = (const float4*)(x8 + (size_t)ovf_t[2 * j + 1] * 8);
                f4add(at0, row[0]);
                f4add(at1, row[1]);
            }
        }
    }
    float inv = 1.0f / (float)max(cif, 1);
    float4* O = (float4*)(agg8 + (size_t)n * 16);
    O[0] = make_float4(ai0.x * inv, ai0.y * inv, ai0.z * inv, ai0.w * inv);
    O[1] = make_float4(ai1.x * inv, ai1.y * inv, ai1.z * inv, ai1.w * inv);
    O[2] = at0;
    O[3] = at1;
}

// hidden gather, GROUP-per-node, CHANNEL-HALVED: 8 lanes per node, 8 nodes
// per wave. In half h, lane (q, r) covers channels 16h+2q..16h+2q+1 of node
// wavebase+r (4-byte slice) -> per-dispatch h16 footprint 3.2 MB (L2-fits).
__global__ __launch_bounds__(256) void k_gather32h(
    const __half* __restrict__ h16, const float* __restrict__ hin,
    const int* __restrict__ csr_i, const int* __restrict__ rs,
    const int* __restrict__ csr_t, const int* __restrict__ cnt_t, int Ct,
    const int* __restrict__ ovf_t, const int* __restrict__ ovfn,
    float* __restrict__ agg, int N, int h) {
    int tid = blockIdx.x * blockDim.x + threadIdx.x;
    int lane = tid & 63;
    int q = lane & 7, r = lane >> 3;
    int g8 = lane & 56;                 // group base lane = r*8
    int nbase = (tid >> 6) << 3;        // 8 nodes per wave
    int n = nbase + r;
    bool valid = (n < N);
    // rs[nbase..nbase+8] via lanes 0..8; cnt_t[nbase..nbase+7] via lanes 0..7
    int rv = 0, cv = 0;
    if (lane < 9) rv = rs[min(nbase + lane, N)];
    if (lane < 8) cv = cnt_t[min(nbase + lane, N - 1)];
    int e0 = __shfl(rv, r, 64);
    int e1 = __shfl(rv, r + 1, 64);
    int ctf = __shfl(cv, r, 64);
    int cif = e1 - e0;
    int ct = min(ctf, Ct);
    int ch = h * 16 + q * 2;            // lane's 2-channel slot
    const __half* xq = h16 + ch;
    // inter relation (mean)
    float2 ai = make_float2(0.f, 0.f);
    for (int base = 0; base < cif; base += 8) {
        int idxv = csr_i[min(e0 + base + q, e1 - 1)];
        gat8d(xq, idxv, g8, base, cif, ai);
    }
    // temp relation (sum)
    float2 at = make_float2(0.f, 0.f);
    for (int base = 0; base < ct; base += 8) {
        int idxv = csr_t[(size_t)n * Ct + min(base + q, ct - 1)];
        gat8d(xq, idxv, g8, base, ct, at);
    }
    if (valid && ctf > Ct) {
        int no = min(ovfn[1], VO);
        for (int j = 0; j < no; ++j) {
            int d = ovf_t[2 * j];
            if (d == n) {
                int s = ovf_t[2 * j + 1];
                const float* hr = hin + (size_t)s * 32 + ch;
                at.x += hr[0];
                at.y += hr[1];
            }
        }
    }
    if (valid) {
        float inv = 1.0f / (float)max(cif, 1);
        *(float2*)(agg + (size_t)n * 64 + ch) = make_float2(ai.x * inv, ai.y * inv);
        *(float2*)(agg + (size_t)n * 64 + 32 + ch) = at;
    }
}

// ---------------- per-node GEMM kernels (weights wave-uniform) ----------------

// seg: 32 input channels; OC outputs with row stride STR (W column offset
// already applied by caller). Weights stay SGPR-loaded (W wave-uniform).
template <int OC, int STR>
__device__ inline void gemm_seg2(const float* __restrict__ seg, const float* __restrict__ W,
                                 float* acc) {
#pragma unroll 2
    for (int k4 = 0; k4 < 8; ++k4) {
        float4 a = ((const float4*)seg)[k4];
        float av[4] = {a.x, a.y, a.z, a.w};
#pragma unroll
        for (int i = 0; i < 4; ++i) {
            const float* Wk = W + (k4 * 4 + i) * STR;
#pragma unroll
            for (int c = 0; c < OC; ++c) acc[c] = fmaf(av[i], Wk[c], acc[c]);
        }
    }
}

// 2-way wave split head: wave parity selects output-channel half. acc[16].
__global__ __launch_bounds__(256) void k_gemm_head(
    const float* __restrict__ agg8, const float* __restrict__ x8,
    const float* __restrict__ Wt, const float* __restrict__ Wi, const float* __restrict__ Wr,
    const float* __restrict__ b, float* __restrict__ hout, __half* __restrict__ h16, int N) {
    int tid = blockIdx.x * blockDim.x + threadIdx.x;
    int lane = tid & 63;
    int n = ((tid >> 7) << 6) + lane;
    if (n >= N) return;
    int co = __builtin_amdgcn_readfirstlane(((tid >> 6) & 1) << 4);
    float acc[16];
#pragma unroll
    for (int c = 0; c < 16; ++c) acc[c] = b[co + c];
    float4 ai0 = ((const float4*)(agg8 + (size_t)n * 16))[0];
    float4 ai1 = ((const float4*)(agg8 + (size_t)n * 16))[1];
    float4 at0 = ((const float4*)(agg8 + (size_t)n * 16 + 8))[0];
    float4 at1 = ((const float4*)(agg8 + (size_t)n * 16 + 8))[1];
    float4 xv0 = ((const float4*)(x8 + (size_t)n * 8))[0];
    float4 xv1 = ((const float4*)(x8 + (size_t)n * 8))[1];
    float a_i[6] = {ai0.x, ai0.y, ai0.z, ai0.w, ai1.x, ai1.y};
    float a_t[6] = {at0.x, at0.y, at0.z, at0.w, at1.x, at1.y};
    float a_x[6] = {xv0.x, xv0.y, xv0.z, xv0.w, xv1.x, xv1.y};
#pragma unroll
    for (int k = 0; k < 6; ++k) {
        const float* Wtk = Wt + k * 32 + co;
        const float* Wik = Wi + k * 32 + co;
        const float* Wrk = Wr + k * 32 + co;
#pragma unroll
        for (int c = 0; c < 16; ++c)
            acc[c] = fmaf(a_t[k], Wtk[c], fmaf(a_i[k], Wik[c], fmaf(a_x[k], Wrk[c], acc[c])));
    }
    float rv[16];
#pragma unroll
    for (int c = 0; c < 16; ++c) rv[c] = fmaxf(acc[c], 0.f);
    float* O = hout + (size_t)n * 32 + co;
#pragma unroll
    for (int c4 = 0; c4 < 4; ++c4)
        ((float4*)O)[c4] = make_float4(rv[c4 * 4 + 0], rv[c4 * 4 + 1],
                                       rv[c4 * 4 + 2], rv[c4 * 4 + 3]);
    __half2 hp[8];
#pragma unroll
    for (int i = 0; i < 8; ++i) hp[i] = __float22half2_rn(make_float2(rv[2 * i], rv[2 * i + 1]));
    uint4* D = (uint4*)(h16 + (size_t)n * 32 + co);
    const uint4* S = (const uint4*)hp;
#pragma unroll
    for (int i = 0; i < 2; ++i) D[i] = S[i];
}

// wave-pair split: wave parity selects output-channel half (co SGPR-uniform),
// node n = 64*(wavepair) + lane. acc[16] -> no spill, 2x waves in flight.
__global__ __launch_bounds__(256) void k_gemm_blk(
    const float* __restrict__ agg, const float* __restrict__ hin,
    const float* __restrict__ Wt, const float* __restrict__ Wi, const float* __restrict__ Wr,
    const float* __restrict__ b, float* __restrict__ hout, __half* __restrict__ h16, int N) {
    int tid = blockIdx.x * blockDim.x + threadIdx.x;
    int lane = tid & 63;
    int n = ((tid >> 7) << 6) + lane;
    if (n >= N) return;
    int co = __builtin_amdgcn_readfirstlane(((tid >> 6) & 1) << 4);
    float acc[16];
#pragma unroll
    for (int c = 0; c < 16; ++c) acc[c] = b[co + c];
    const float* Ai = agg + (size_t)n * 64;
    const float* At = Ai + 32;
    const float* H = hin + (size_t)n * 32;
    gemm_seg2<16, 32>(At, Wt + co, acc);
    gemm_seg2<16, 32>(Ai, Wi + co, acc);
    gemm_seg2<16, 32>(H, Wr + co, acc);
    const float* Hc = H + co;
    float rv[16];
#pragma unroll
    for (int c4 = 0; c4 < 4; ++c4) {
        float4 hv = ((const float4*)Hc)[c4];
        rv[c4 * 4 + 0] = fmaxf(acc[c4 * 4 + 0], 0.f) + hv.x;
        rv[c4 * 4 + 1] = fmaxf(acc[c4 * 4 + 1], 0.f) + hv.y;
        rv[c4 * 4 + 2] = fmaxf(acc[c4 * 4 + 2], 0.f) + hv.z;
        rv[c4 * 4 + 3] = fmaxf(acc[c4 * 4 + 3], 0.f) + hv.w;
    }
    float* O = hout + (size_t)n * 32 + co;
#pragma unroll
    for (int c4 = 0; c4 < 4; ++c4)
        ((float4*)O)[c4] = make_float4(rv[c4 * 4 + 0], rv[c4 * 4 + 1],
                                       rv[c4 * 4 + 2], rv[c4 * 4 + 3]);
    __half2 hp[8];
#pragma unroll
    for (int i = 0; i < 8; ++i) hp[i] = __float22half2_rn(make_float2(rv[2 * i], rv[2 * i + 1]));
    uint4* D = (uint4*)(h16 + (size_t)n * 32 + co);
    const uint4* S = (const uint4*)hp;
#pragma unroll
    for (int i = 0; i < 2; ++i) D[i] = S[i];
}

// 4-way wave split: wave&3 selects 16-channel output slice of 64. acc[16].
__global__ __launch_bounds__(256) void k_gemm_last(
    const float* __restrict__ agg, const float* __restrict__ hin,
    const float* __restrict__ Wt, const float* __restrict__ Wi, const float* __restrict__ Wr,
    const float* __restrict__ b, const float* __restrict__ proj, float* __restrict__ out, int N) {
    int tid = blockIdx.x * blockDim.x + threadIdx.x;
    int lane = tid & 63;
    int w = tid >> 6;
    int n = ((w >> 2) << 6) + lane;
    if (n >= N) return;
    int co = __builtin_amdgcn_readfirstlane((w & 3) << 4);
    float acc[16];
#pragma unroll
    for (int c = 0; c < 16; ++c) acc[c] = b[co + c];
    const float* Ai = agg + (size_t)n * 64;
    const float* At = Ai + 32;
    const float* H = hin + (size_t)n * 32;
    gemm_seg2<16, 64>(At, Wt + co, acc);
    gemm_seg2<16, 64>(Ai, Wi + co, acc);
    gemm_seg2<16, 64>(H, Wr + co, acc);
#pragma unroll
    for (int c = 0; c < 16; ++c) acc[c] = fmaxf(acc[c], 0.f);
    gemm_seg2<16, 64>(H, proj + co, acc);
    float* O = out + (size_t)n * 64 + co;
#pragma unroll
    for (int c4 = 0; c4 < 4; ++c4)
        ((float4*)O)[c4] = make_float4(acc[c4 * 4 + 0], acc[c4 * 4 + 1],
                                       acc[c4 * 4 + 2], acc[c4 * 4 + 3]);
}

// ---------------- launch ----------------

static inline size_t align256(size_t x) { return (x + 255) & ~(size_t)255; }

extern "C" void kernel_launch(void* const* d_in, const int* in_sizes, int n_in,
                              void* d_out, int out_size, void* d_ws, size_t ws_size,
                              hipStream_t stream) {
    const float* x_stroke = (const float*)d_in[0];
    const int* ei_temp = (const int*)d_in[1];
    const int* ei_inter = (const int*)d_in[2];
    const float* head_Wt = (const float*)d_in[3];
    const float* head_Wi = (const float*)d_in[4];
    const float* head_Wr = (const float*)d_in[5];
    const float* head_b = (const float*)d_in[6];
    const float* blk_Wt = (const float*)d_in[7];
    const float* blk_Wi = (const float*)d_in[8];
    const float* blk_Wr = (const float*)d_in[9];
    const float* blk_b = (const float*)d_in[10];
    const float* last_Wt = (const float*)d_in[11];
    const float* last_Wi = (const float*)d_in[12];
    const float* last_Wr = (const float*)d_in[13];
    const float* last_b = (const float*)d_in[14];
    const float* last_proj = (const float*)d_in[15];

    const int N = in_sizes[0] / 6;
    const int Et = in_sizes[1] / 2;
    const int Ei = in_sizes[2] / 2;

    const int* temp_src = ei_temp;
    const int* temp_dst = ei_temp + Et;
    const int* int_src = ei_inter;
    const int* int_dst = ei_inter + Ei;

    const int shift = 7;                      // 128-node buckets
    const int NB = ((N - 1) >> shift) + 1;    // assumes N <= 131072

    char* p = (char*)d_ws;
    size_t off = 0;
    auto carve = [&](size_t bytes) {
        char* r = p + off;
        off = align256(off + bytes);
        return r;
    };
    // zero-init block: cnt_t, ovfn, gh contiguous -> ONE memset
    int* cnt_t = (int*)carve((size_t)N * 4);
    int* ovfn = (int*)carve(2 * 4);
    int* gh = (int*)carve((size_t)NB * 4);
    size_t zspan = (size_t)((char*)gh + (size_t)NB * 4 - (char*)cnt_t);
    int* ovf_t = (int*)carve((size_t)VO * 8);
    int* boff = (int*)carve((size_t)(NB + 1) * 4);
    int* cur = (int*)carve((size_t)NB * 4);
    int* rs = (int*)carve((size_t)(N + 1) * 4);
    float* x8 = (float*)carve((size_t)N * 8 * 4);
    float* bufA = (float*)carve((size_t)N * 32 * 4);
    float* bufD = (float*)carve((size_t)N * 32 * 4);
    float* agg = (float*)carve((size_t)N * 64 * 4);   // also holds agg8 [N,16]
    __half* h16 = (__half*)carve((size_t)N * 32 * 2); // fp16 gather staging
    int* ebuf = (int*)carve((size_t)Ei * 4);          // packed (src<<7 | dst&127)
    int* csr_i = (int*)carve((size_t)Ei * 4);         // dense
    const int Ct = 16;
    int* csr_t = (int*)carve((size_t)N * Ct * 4);
    (void)ws_size;

    const int B = 256;
    auto blocks = [&](long long work) { return (int)((work + B - 1) / B); };

    hipMemsetAsync(cnt_t, 0, zspan, stream);

    k_hist<<<256, B, 0, stream>>>(int_dst, Ei, gh, NB, shift);
    k_scan_b<<<1, 1024, 0, stream>>>(gh, NB, boff, cur);
    k_scatter<<<(int)((Ei + SCAT_SPAN - 1) / SCAT_SPAN), SCAT_THR, 0, stream>>>(
        int_src, int_dst, Ei, shift, NB, cur, ebuf);
    k_fill3<<<NB, B, 0, stream>>>(ebuf, boff, NB, rs, csr_i, N);
    k_fill2<<<blocks(Et), B, 0, stream>>>(temp_src, temp_dst, Et, cnt_t, csr_t, Ct, ovf_t, &ovfn[1]);
    k_pad_x<<<blocks((long long)N * 8), B, 0, stream>>>(x_stroke, x8, N);

    // wave-split GEMM grids
    const int gw2 = 2 * ((N + 63) >> 6);              // 2 waves per 64 nodes
    const int gblocks2 = ((gw2 << 6) + B - 1) / B;
    const int gw4 = 4 * ((N + 63) >> 6);              // 4 waves per 64 nodes
    const int gblocks4 = ((gw4 << 6) + B - 1) / B;
    // group-per-node gather grid: 8 nodes per wave
    const int gatherW = (N + 7) >> 3;
    const int gatherBlocks = (int)(((long long)gatherW * 64 + B - 1) / B);

    // head
    k_gather_head<<<blocks(N), B, 0, stream>>>(
        x8, csr_i, rs, csr_t, cnt_t, Ct, ovf_t, ovfn, agg, N);
    k_gemm_head<<<gblocks2, B, 0, stream>>>(agg, x8, head_Wt, head_Wi, head_Wr, head_b,
                                            bufA, h16, N);

    // 3 hidden residual blocks (gather split into two L2-resident halves)
    float* hin = bufA;
    float* hout = bufD;
    for (int i = 0; i < 3; ++i) {
        k_gather32h<<<gatherBlocks, B, 0, stream>>>(
            h16, hin, csr_i, rs, csr_t, cnt_t, Ct, ovf_t, ovfn, agg, N, 0);
        k_gather32h<<<gatherBlocks, B, 0, stream>>>(
            h16, hin, csr_i, rs, csr_t, cnt_t, Ct, ovf_t, ovfn, agg, N, 1);
        k_gemm_blk<<<gblocks2, B, 0, stream>>>(
            agg, hin, blk_Wt + (size_t)i * 32 * 32, blk_Wi + (size_t)i * 32 * 32,
            blk_Wr + (size_t)i * 32 * 32, blk_b + (size_t)i * 32, hout, h16, N);
        float* t = hin; hin = hout; hout = t;
    }

    // last
    k_gather32h<<<gatherBlocks, B, 0, stream>>>(
        h16, hin, csr_i, rs, csr_t, cnt_t, Ct, ovf_t, ovfn, agg, N, 0);
    k_gather32h<<<gatherBlocks, B, 0, stream>>>(
        h16, hin, csr_i, rs, csr_t, cnt_t, Ct, ovf_t, ovfn, agg, N, 1);
    k_gemm_last<<<gblocks4, B, 0, stream>>>(agg, hin, last_Wt, last_Wi, last_Wr, last_b,
                                            last_proj, (float*)d_out, N);
}

// Round 15
// 503.220 us; speedup vs baseline: 1.3080x; 1.3080x over previous
//
#include <hip/hip_runtime.h>
#include <hip/hip_fp16.h>

// Hetero-GNN: 5 layers of relu(segsum_temp(x)@Wt + segmean_inter(x)@Wi + x@Wr + b)
// (aggregation commuted past the matmuls).
//
// R24 = exact revert to R22/R19 (best verified: 511.4-513.7 us).
//  - R23 POST-MORTEM (final gather experiment): channel-halved L2-resident
//    gather FAILED its falsification test -- per-half FETCH 119.5 MB (!= the
//    predicted ~38 MB): the 12.8 MB csr stream evicts the 3.2 MB h16 half
//    from per-XCD L2, and line-granular fetches don't shrink with slice
//    width. Conclusion: k_gather32 is at its practical floor for this layout;
//    falsified levers: deeper batches (R20), lane regrouping (R21), occupancy
//    (R11/R18), L2-residency split (R23).
//  - Landed techniques: dense CSR via LDS write-combined scatter (R12) +
//    group-per-bucket copy-out (R19); fp16 gather staging (R13);
//    group-per-node gather, no cross-lane reduce (R15); thread-per-node head
//    gather (R16); acc[16] wave-split GEMMs (R10/R14).

#define VO 8192        // overflow list capacity (pairs), temp relation
#define FCAP 10240     // staged edges per bucket in k_fill3 (40 KB LDS)
#define SCAT_THR 512
#define SCAT_SPAN 8192 // edges per scatter block (32 KB LDS stage)

typedef float vf4 __attribute__((ext_vector_type(4)));
typedef float vf2 __attribute__((ext_vector_type(2)));

__device__ inline void f4add(float4& a, const float4& v) {
    a.x += v.x; a.y += v.y; a.z += v.z; a.w += v.w;
}

__device__ inline float4 cvt8(vf2 v) {
    union { vf2 f; __half2 h[2]; } u;
    u.f = v;
    float2 a = __half22float2(u.h[0]);
    float2 b = __half22float2(u.h[1]);
    return make_float4(a.x, a.y, b.x, b.y);
}

// ---------------- build: hist -> scan -> scatter -> dense fill ----------------

__global__ void k_hist(const int* __restrict__ dst, int E, int* __restrict__ gh,
                       int NB, int shift) {
    __shared__ int sh[1024];
    for (int j = threadIdx.x; j < NB; j += blockDim.x) sh[j] = 0;
    __syncthreads();
    for (int i = blockIdx.x * blockDim.x + threadIdx.x; i < E; i += gridDim.x * blockDim.x)
        atomicAdd(&sh[dst[i] >> shift], 1);
    __syncthreads();
    for (int j = threadIdx.x; j < NB; j += blockDim.x)
        if (sh[j]) atomicAdd(&gh[j], sh[j]);
}

__global__ void k_scan_b(const int* __restrict__ gh, int NB, int* __restrict__ boff,
                         int* __restrict__ cur) {
    __shared__ int sh[1024];
    int t = threadIdx.x;
    sh[t] = (t < NB) ? gh[t] : 0;
    __syncthreads();
    for (int off = 1; off < 1024; off <<= 1) {
        int v = (t >= off) ? sh[t - off] : 0;
        __syncthreads();
        sh[t] += v;
        __syncthreads();
    }
    if (t < NB) {
        int ex = t ? sh[t - 1] : 0;
        boff[t] = ex;
        cur[t] = ex;
    }
    if (t == 0) boff[NB] = sh[NB - 1];
}

// write-combined scatter: count -> scan -> chunk alloc -> rank into LDS stage
// (bucket-major) -> group-per-bucket burst copy-out.
__global__ __launch_bounds__(512) void k_scatter(const int* __restrict__ src,
                                                 const int* __restrict__ dst, int E,
                                                 int shift, int NB, int* __restrict__ cur,
                                                 int* __restrict__ ebuf) {
    __shared__ int lh[1024];     // per-bucket counts
    __shared__ int lb[1024];     // per-bucket global base (chunk alloc)
    __shared__ int lstart[1024]; // per-bucket LDS stage start (exclusive scan)
    __shared__ int lcur[1024];   // ranking cursors
    __shared__ int wsum[8];
    __shared__ int stage[SCAT_SPAN];
    const int t = threadIdx.x;
    const int lane = t & 63;
    const int wv = t >> 6;
    int lo = blockIdx.x * SCAT_SPAN;
    int hi = min(E, lo + SCAT_SPAN);
    for (int j = t; j < 1024; j += 512) lh[j] = 0;
    __syncthreads();
    // pass A: count
    for (int e = lo + t; e < hi; e += 512)
        atomicAdd(&lh[dst[e] >> shift], 1);
    __syncthreads();
    // exclusive scan of lh[0..1023] -> lstart (2 elems/thread, wave shfl scan)
    int a0 = lh[2 * t], a1 = lh[2 * t + 1];
    int ts = a0 + a1;
    int run = ts;
#pragma unroll
    for (int off = 1; off < 64; off <<= 1) {
        int v = __shfl_up(run, off, 64);
        if (lane >= off) run += v;
    }
    if (lane == 63) wsum[wv] = run;
    __syncthreads();
    int wpre = 0;
#pragma unroll
    for (int w = 0; w < 8; ++w) wpre += (w < wv) ? wsum[w] : 0;
    int excl = wpre + run - ts;
    lstart[2 * t] = excl;
    lstart[2 * t + 1] = excl + a0;
    lcur[2 * t] = excl;
    lcur[2 * t + 1] = excl + a0;
    // global chunk alloc (contiguous per bucket via cur[] cursors)
    for (int j = t; j < NB; j += 512) {
        int c = lh[j];
        lb[j] = c ? atomicAdd(&cur[j], c) : 0;
    }
    __syncthreads();
    // pass B: re-read + rank into bucket-major LDS stage
    const int mask = (1 << shift) - 1;
    for (int e = lo + t; e < hi; e += 512) {
        int s = src[e];
        int d = dst[e];
        int p = atomicAdd(&lcur[d >> shift], 1);
        stage[p] = (s << shift) | (d & mask);
    }
    __syncthreads();
    // copy-out: 8 lane-groups of 8 per wave; each group streams one bucket's
    // contiguous run -> ~13 sweeps instead of 98, 4x lane utilization.
    const int grp = lane >> 3;
    const int gl = lane & 7;
    const int gid = wv * 8 + grp;     // 0..63
    for (int j = gid; j < NB; j += 64) {
        int c = lh[j];
        int sb = lstart[j];
        int gb = lb[j];
        for (int i = gl; i < c; i += 8)
            ebuf[gb + i] = stage[sb + i];
    }
}

// dense CSR fill: one block per 128-node bucket. Two streaming passes over the
// bucket's packed ebuf segment; LDS staging -> coalesced full-line csr writes.
__global__ __launch_bounds__(256) void k_fill3(const int* __restrict__ ebuf,
                                               const int* __restrict__ boff, int NB,
                                               int* __restrict__ rs, int* __restrict__ csr,
                                               int N) {
    __shared__ int hist[128];
    __shared__ int offs[129];
    __shared__ int curl[128];
    __shared__ int scn[128];
    __shared__ int stage[FCAP];
    int b = blockIdx.x;
    if (b >= NB) return;
    int lo = boff[b], hi = boff[b + 1];
    int cnt = hi - lo;
    int base = b << 7;
    int t = threadIdx.x;
    for (int i = t; i < 128; i += 256) { hist[i] = 0; curl[i] = 0; }
    __syncthreads();
    // pass 1: count
    for (int e = lo + t; e < hi; e += 256) {
        int v = ebuf[e];
        atomicAdd(&hist[v & 127], 1);
    }
    __syncthreads();
    // parallel exclusive scan of hist -> offs (Hillis-Steele over 128)
    if (t < 128) scn[t] = hist[t];
    __syncthreads();
    for (int off = 1; off < 128; off <<= 1) {
        int v = (t >= off && t < 128) ? scn[t - off] : 0;
        __syncthreads();
        if (t < 128) scn[t] += v;
        __syncthreads();
    }
    if (t < 128) offs[t] = scn[t] - hist[t];
    if (t == 0) offs[128] = scn[127];
    __syncthreads();
    // rs offsets (exact; dst < N so nodes >= N have count 0)
    for (int i = t; i < 128; i += 256) {
        int g = base + i;
        if (g < N) rs[g] = lo + offs[i];
    }
    if (b == NB - 1 && t == 0) rs[N] = hi;
    // pass 2: place
    bool staged = (cnt <= FCAP);
    for (int e = lo + t; e < hi; e += 256) {
        int v = ebuf[e];
        int dl = v & 127;
        int sidx = (int)(((unsigned)v) >> 7);
        int p = offs[dl] + atomicAdd(&curl[dl], 1);
        if (staged) stage[p] = sidx;
        else csr[lo + p] = sidx;
    }
    __syncthreads();
    if (staged)
        for (int i = t; i < cnt; i += 256) csr[lo + i] = stage[i];
}

// temp relation (100k edges): padded one-pass fill
__global__ void k_fill2(const int* __restrict__ src, const int* __restrict__ dst, int E,
                        int* __restrict__ cnt, int* __restrict__ csr, int C,
                        int* __restrict__ ovf, int* __restrict__ ovf_n) {
    int i = blockIdx.x * blockDim.x + threadIdx.x;
    if (i >= E) return;
    int s = src[i];
    int d = dst[i];
    int slot = atomicAdd(&cnt[d], 1);
    if (slot < C) {
        csr[(size_t)d * C + slot] = s;
    } else {
        int p = atomicAdd(ovf_n, 1);
        if (p < VO) { ovf[2 * p] = d; ovf[2 * p + 1] = s; }
    }
}

__global__ void k_pad_x(const float* __restrict__ x, float* __restrict__ x8, int N) {
    int i = blockIdx.x * blockDim.x + threadIdx.x;
    if (i >= N * 8) return;
    int n = i >> 3, c = i & 7;
    x8[i] = (c < 6) ? x[n * 6 + c] : 0.0f;
}

// ---------------- gathers ----------------

// group gather: 8 edges per batch from idxv (lane q of group holds edge base+q
// index), 8 row loads in flight, ONE vmcnt(0). xq = h16 + q*4 (lane's slice).
__device__ inline void gat8_h16(const __half* __restrict__ xq, int idxv, int g8,
                                int base, int cif, float4& acc) {
    int s[8];
#pragma unroll
    for (int j = 0; j < 8; ++j) s[j] = __shfl(idxv, g8 + j, 64);
    const __half* a0 = xq + (size_t)s[0] * 32;
    const __half* a1 = xq + (size_t)s[1] * 32;
    const __half* a2 = xq + (size_t)s[2] * 32;
    const __half* a3 = xq + (size_t)s[3] * 32;
    const __half* a4 = xq + (size_t)s[4] * 32;
    const __half* a5 = xq + (size_t)s[5] * 32;
    const __half* a6 = xq + (size_t)s[6] * 32;
    const __half* a7 = xq + (size_t)s[7] * 32;
    vf2 w0, w1, w2, w3, w4, w5, w6, w7;
    asm volatile(
        "global_load_dwordx2 %0, %8, off\n\t"
        "global_load_dwordx2 %1, %9, off\n\t"
        "global_load_dwordx2 %2, %10, off\n\t"
        "global_load_dwordx2 %3, %11, off\n\t"
        "global_load_dwordx2 %4, %12, off\n\t"
        "global_load_dwordx2 %5, %13, off\n\t"
        "global_load_dwordx2 %6, %14, off\n\t"
        "global_load_dwordx2 %7, %15, off\n\t"
        "s_waitcnt vmcnt(0)"
        : "=&v"(w0), "=&v"(w1), "=&v"(w2), "=&v"(w3),
          "=&v"(w4), "=&v"(w5), "=&v"(w6), "=&v"(w7)
        : "v"(a0), "v"(a1), "v"(a2), "v"(a3), "v"(a4), "v"(a5), "v"(a6), "v"(a7)
        : "memory");
    float4 v0 = cvt8(w0), v1 = cvt8(w1), v2 = cvt8(w2), v3 = cvt8(w3);
    float4 v4 = cvt8(w4), v5 = cvt8(w5), v6 = cvt8(w6), v7 = cvt8(w7);
    if (base + 8 <= cif) {
        acc.x += (v0.x + v1.x) + (v2.x + v3.x) + (v4.x + v5.x) + (v6.x + v7.x);
        acc.y += (v0.y + v1.y) + (v2.y + v3.y) + (v4.y + v5.y) + (v6.y + v7.y);
        acc.z += (v0.z + v1.z) + (v2.z + v3.z) + (v4.z + v5.z) + (v6.z + v7.z);
        acc.w += (v0.w + v1.w) + (v2.w + v3.w) + (v4.w + v5.w) + (v6.w + v7.w);
    } else {
        float4 vv[8] = {v0, v1, v2, v3, v4, v5, v6, v7};
#pragma unroll
        for (int j = 0; j < 8; ++j) {
            float m = (base + j < cif) ? 1.0f : 0.0f;
            acc.x = fmaf(m, vv[j].x, acc.x);
            acc.y = fmaf(m, vv[j].y, acc.y);
            acc.z = fmaf(m, vv[j].z, acc.z);
            acc.w = fmaf(m, vv[j].w, acc.w);
        }
    }
}

// head gather, THREAD-per-node: lane owns full 8-ch fp32 row accumulators.
// Contiguous CSR segment walked in batches of 4 (4 idx + 8 float4 loads).
__global__ __launch_bounds__(256) void k_gather_head(
    const float* __restrict__ x8, const int* __restrict__ csr_i, const int* __restrict__ rs,
    const int* __restrict__ csr_t, const int* __restrict__ cnt_t, int Ct,
    const int* __restrict__ ovf_t, const int* __restrict__ ovfn,
    float* __restrict__ agg8, int N) {
    int n = blockIdx.x * blockDim.x + threadIdx.x;
    if (n >= N) return;
    int e0 = rs[n], e1 = rs[n + 1];
    int cif = e1 - e0;
    int ctf = cnt_t[n], ct = min(ctf, Ct);
    float4 ai0 = make_float4(0.f, 0.f, 0.f, 0.f), ai1 = ai0;
    for (int base = 0; base < cif; base += 4) {
        int sj[4];
#pragma unroll
        for (int j = 0; j < 4; ++j) sj[j] = csr_i[e0 + min(base + j, cif - 1)];
        float4 lo[4], hi[4];
#pragma unroll
        for (int j = 0; j < 4; ++j) {
            const float4* row = (const float4*)(x8 + (size_t)sj[j] * 8);
            lo[j] = row[0];
            hi[j] = row[1];
        }
#pragma unroll
        for (int j = 0; j < 4; ++j) {
            float m = (base + j < cif) ? 1.0f : 0.0f;
            ai0.x = fmaf(m, lo[j].x, ai0.x);
            ai0.y = fmaf(m, lo[j].y, ai0.y);
            ai0.z = fmaf(m, lo[j].z, ai0.z);
            ai0.w = fmaf(m, lo[j].w, ai0.w);
            ai1.x = fmaf(m, hi[j].x, ai1.x);
            ai1.y = fmaf(m, hi[j].y, ai1.y);
            ai1.z = fmaf(m, hi[j].z, ai1.z);
            ai1.w = fmaf(m, hi[j].w, ai1.w);
        }
    }
    float4 at0 = make_float4(0.f, 0.f, 0.f, 0.f), at1 = at0;
    for (int base = 0; base < ct; base += 4) {
        int sj[4];
#pragma unroll
        for (int j = 0; j < 4; ++j) sj[j] = csr_t[(size_t)n * Ct + min(base + j, ct - 1)];
        float4 lo[4], hi[4];
#pragma unroll
        for (int j = 0; j < 4; ++j) {
            const float4* row = (const float4*)(x8 + (size_t)sj[j] * 8);
            lo[j] = row[0];
            hi[j] = row[1];
        }
#pragma unroll
        for (int j = 0; j < 4; ++j) {
            float m = (base + j < ct) ? 1.0f : 0.0f;
            at0.x = fmaf(m, lo[j].x, at0.x);
            at0.y = fmaf(m, lo[j].y, at0.y);
            at0.z = fmaf(m, lo[j].z, at0.z);
            at0.w = fmaf(m, lo[j].w, at0.w);
            at1.x = fmaf(m, hi[j].x, at1.x);
            at1.y = fmaf(m, hi[j].y, at1.y);
            at1.z = fmaf(m, hi[j].z, at1.z);
            at1.w = fmaf(m, hi[j].w, at1.w);
        }
    }
    if (ctf > Ct) {
        int no = min(ovfn[1], VO);
        for (int j = 0; j < no; ++j) {
            int d = ovf_t[2 * j];
            if (d == n) {
                const float4* row = (const float4*)(x8 + (size_t)ovf_t[2 * j + 1] * 8);
                f4add(at0, row[0]);
                f4add(at1, row[1]);
            }
        }
    }
    float inv = 1.0f / (float)max(cif, 1);
    float4* O = (float4*)(agg8 + (size_t)n * 16);
    O[0] = make_float4(ai0.x * inv, ai0.y * inv, ai0.z * inv, ai0.w * inv);
    O[1] = make_float4(ai1.x * inv, ai1.y * inv, ai1.z * inv, ai1.w * inv);
    O[2] = at0;
    O[3] = at1;
}

// hidden gather, GROUP-per-node: 8 lanes per node, 8 nodes per wave.
// lane (q, r): channels 4q..4q+3 of node wavebase+r. No cross-lane reduction.
__global__ __launch_bounds__(256) void k_gather32(
    const __half* __restrict__ h16, const float* __restrict__ hin,
    const int* __restrict__ csr_i, const int* __restrict__ rs,
    const int* __restrict__ csr_t, const int* __restrict__ cnt_t, int Ct,
    const int* __restrict__ ovf_t, const int* __restrict__ ovfn,
    float* __restrict__ agg, int N) {
    int tid = blockIdx.x * blockDim.x + threadIdx.x;
    int lane = tid & 63;
    int q = lane & 7, r = lane >> 3;
    int g8 = lane & 56;                 // group base lane = r*8
    int nbase = (tid >> 6) << 3;        // 8 nodes per wave
    int n = nbase + r;
    bool valid = (n < N);
    // rs[nbase..nbase+8] via lanes 0..8; cnt_t[nbase..nbase+7] via lanes 0..7
    int rv = 0, cv = 0;
    if (lane < 9) rv = rs[min(nbase + lane, N)];
    if (lane < 8) cv = cnt_t[min(nbase + lane, N - 1)];
    int e0 = __shfl(rv, r, 64);
    int e1 = __shfl(rv, r + 1, 64);
    int ctf = __shfl(cv, r, 64);
    int cif = e1 - e0;
    int ct = min(ctf, Ct);
    const __half* xq = h16 + q * 4;     // lane's 8-byte channel slice
    // inter relation (mean)
    float4 ai = make_float4(0.f, 0.f, 0.f, 0.f);
    for (int base = 0; base < cif; base += 8) {
        int idxv = csr_i[min(e0 + base + q, e1 - 1)];
        gat8_h16(xq, idxv, g8, base, cif, ai);
    }
    // temp relation (sum)
    float4 at = make_float4(0.f, 0.f, 0.f, 0.f);
    for (int base = 0; base < ct; base += 8) {
        int idxv = csr_t[(size_t)n * Ct + min(base + q, ct - 1)];
        gat8_h16(xq, idxv, g8, base, ct, at);
    }
    if (valid && ctf > Ct) {
        int no = min(ovfn[1], VO);
        for (int j = 0; j < no; ++j) {
            int d = ovf_t[2 * j];
            if (d == n) {
                int s = ovf_t[2 * j + 1];
                f4add(at, *(const float4*)(hin + (size_t)s * 32 + q * 4));
            }
        }
    }
    if (valid) {
        float inv = 1.0f / (float)max(cif, 1);
        *(float4*)(agg + (size_t)n * 64 + q * 4) =
            make_float4(ai.x * inv, ai.y * inv, ai.z * inv, ai.w * inv);
        *(float4*)(agg + (size_t)n * 64 + 32 + q * 4) = at;
    }
}

// ---------------- per-node GEMM kernels (weights wave-uniform) ----------------

// seg: 32 input channels; OC outputs with row stride STR (W column offset
// already applied by caller). Weights stay SGPR-loaded (W wave-uniform).
template <int OC, int STR>
__device__ inline void gemm_seg2(const float* __restrict__ seg, const float* __restrict__ W,
                                 float* acc) {
#pragma unroll 2
    for (int k4 = 0; k4 < 8; ++k4) {
        float4 a = ((const float4*)seg)[k4];
        float av[4] = {a.x, a.y, a.z, a.w};
#pragma unroll
        for (int i = 0; i < 4; ++i) {
            const float* Wk = W + (k4 * 4 + i) * STR;
#pragma unroll
            for (int c = 0; c < OC; ++c) acc[c] = fmaf(av[i], Wk[c], acc[c]);
        }
    }
}

// 2-way wave split head: wave parity selects output-channel half. acc[16].
__global__ __launch_bounds__(256) void k_gemm_head(
    const float* __restrict__ agg8, const float* __restrict__ x8,
    const float* __restrict__ Wt, const float* __restrict__ Wi, const float* __restrict__ Wr,
    const float* __restrict__ b, float* __restrict__ hout, __half* __restrict__ h16, int N) {
    int tid = blockIdx.x * blockDim.x + threadIdx.x;
    int lane = tid & 63;
    int n = ((tid >> 7) << 6) + lane;
    if (n >= N) return;
    int co = __builtin_amdgcn_readfirstlane(((tid >> 6) & 1) << 4);
    float acc[16];
#pragma unroll
    for (int c = 0; c < 16; ++c) acc[c] = b[co + c];
    float4 ai0 = ((const float4*)(agg8 + (size_t)n * 16))[0];
    float4 ai1 = ((const float4*)(agg8 + (size_t)n * 16))[1];
    float4 at0 = ((const float4*)(agg8 + (size_t)n * 16 + 8))[0];
    float4 at1 = ((const float4*)(agg8 + (size_t)n * 16 + 8))[1];
    float4 xv0 = ((const float4*)(x8 + (size_t)n * 8))[0];
    float4 xv1 = ((const float4*)(x8 + (size_t)n * 8))[1];
    float a_i[6] = {ai0.x, ai0.y, ai0.z, ai0.w, ai1.x, ai1.y};
    float a_t[6] = {at0.x, at0.y, at0.z, at0.w, at1.x, at1.y};
    float a_x[6] = {xv0.x, xv0.y, xv0.z, xv0.w, xv1.x, xv1.y};
#pragma unroll
    for (int k = 0; k < 6; ++k) {
        const float* Wtk = Wt + k * 32 + co;
        const float* Wik = Wi + k * 32 + co;
        const float* Wrk = Wr + k * 32 + co;
#pragma unroll
        for (int c = 0; c < 16; ++c)
            acc[c] = fmaf(a_t[k], Wtk[c], fmaf(a_i[k], Wik[c], fmaf(a_x[k], Wrk[c], acc[c])));
    }
    float rv[16];
#pragma unroll
    for (int c = 0; c < 16; ++c) rv[c] = fmaxf(acc[c], 0.f);
    float* O = hout + (size_t)n * 32 + co;
#pragma unroll
    for (int c4 = 0; c4 < 4; ++c4)
        ((float4*)O)[c4] = make_float4(rv[c4 * 4 + 0], rv[c4 * 4 + 1],
                                       rv[c4 * 4 + 2], rv[c4 * 4 + 3]);
    __half2 hp[8];
#pragma unroll
    for (int i = 0; i < 8; ++i) hp[i] = __float22half2_rn(make_float2(rv[2 * i], rv[2 * i + 1]));
    uint4* D = (uint4*)(h16 + (size_t)n * 32 + co);
    const uint4* S = (const uint4*)hp;
#pragma unroll
    for (int i = 0; i < 2; ++i) D[i] = S[i];
}

// wave-pair split: wave parity selects output-channel half (co SGPR-uniform),
// node n = 64*(wavepair) + lane. acc[16] -> no spill, 2x waves in flight.
__global__ __launch_bounds__(256) void k_gemm_blk(
    const float* __restrict__ agg, const float* __restrict__ hin,
    const float* __restrict__ Wt, const float* __restrict__ Wi, const float* __restrict__ Wr,
    const float* __restrict__ b, float* __restrict__ hout, __half* __restrict__ h16, int N) {
    int tid = blockIdx.x * blockDim.x + threadIdx.x;
    int lane = tid & 63;
    int n = ((tid >> 7) << 6) + lane;
    if (n >= N) return;
    int co = __builtin_amdgcn_readfirstlane(((tid >> 6) & 1) << 4);
    float acc[16];
#pragma unroll
    for (int c = 0; c < 16; ++c) acc[c] = b[co + c];
    const float* Ai = agg + (size_t)n * 64;
    const float* At = Ai + 32;
    const float* H = hin + (size_t)n * 32;
    gemm_seg2<16, 32>(At, Wt + co, acc);
    gemm_seg2<16, 32>(Ai, Wi + co, acc);
    gemm_seg2<16, 32>(H, Wr + co, acc);
    const float* Hc = H + co;
    float rv[16];
#pragma unroll
    for (int c4 = 0; c4 < 4; ++c4) {
        float4 hv = ((const float4*)Hc)[c4];
        rv[c4 * 4 + 0] = fmaxf(acc[c4 * 4 + 0], 0.f) + hv.x;
        rv[c4 * 4 + 1] = fmaxf(acc[c4 * 4 + 1], 0.f) + hv.y;
        rv[c4 * 4 + 2] = fmaxf(acc[c4 * 4 + 2], 0.f) + hv.z;
        rv[c4 * 4 + 3] = fmaxf(acc[c4 * 4 + 3], 0.f) + hv.w;
    }
    float* O = hout + (size_t)n * 32 + co;
#pragma unroll
    for (int c4 = 0; c4 < 4; ++c4)
        ((float4*)O)[c4] = make_float4(rv[c4 * 4 + 0], rv[c4 * 4 + 1],
                                       rv[c4 * 4 + 2], rv[c4 * 4 + 3]);
    __half2 hp[8];
#pragma unroll
    for (int i = 0; i < 8; ++i) hp[i] = __float22half2_rn(make_float2(rv[2 * i], rv[2 * i + 1]));
    uint4* D = (uint4*)(h16 + (size_t)n * 32 + co);
    const uint4* S = (const uint4*)hp;
#pragma unroll
    for (int i = 0; i < 2; ++i) D[i] = S[i];
}

// 4-way wave split: wave&3 selects 16-channel output slice of 64. acc[16].
__global__ __launch_bounds__(256) void k_gemm_last(
    const float* __restrict__ agg, const float* __restrict__ hin,
    const float* __restrict__ Wt, const float* __restrict__ Wi, const float* __restrict__ Wr,
    const float* __restrict__ b, const float* __restrict__ proj, float* __restrict__ out, int N) {
    int tid = blockIdx.x * blockDim.x + threadIdx.x;
    int lane = tid & 63;
    int w = tid >> 6;
    int n = ((w >> 2) << 6) + lane;
    if (n >= N) return;
    int co = __builtin_amdgcn_readfirstlane((w & 3) << 4);
    float acc[16];
#pragma unroll
    for (int c = 0; c < 16; ++c) acc[c] = b[co + c];
    const float* Ai = agg + (size_t)n * 64;
    const float* At = Ai + 32;
    const float* H = hin + (size_t)n * 32;
    gemm_seg2<16, 64>(At, Wt + co, acc);
    gemm_seg2<16, 64>(Ai, Wi + co, acc);
    gemm_seg2<16, 64>(H, Wr + co, acc);
#pragma unroll
    for (int c = 0; c < 16; ++c) acc[c] = fmaxf(acc[c], 0.f);
    gemm_seg2<16, 64>(H, proj + co, acc);
    float* O = out + (size_t)n * 64 + co;
#pragma unroll
    for (int c4 = 0; c4 < 4; ++c4)
        ((float4*)O)[c4] = make_float4(acc[c4 * 4 + 0], acc[c4 * 4 + 1],
                                       acc[c4 * 4 + 2], acc[c4 * 4 + 3]);
}

// ---------------- launch ----------------

static inline size_t align256(size_t x) { return (x + 255) & ~(size_t)255; }

extern "C" void kernel_launch(void* const* d_in, const int* in_sizes, int n_in,
                              void* d_out, int out_size, void* d_ws, size_t ws_size,
                              hipStream_t stream) {
    const float* x_stroke = (const float*)d_in[0];
    const int* ei_temp = (const int*)d_in[1];
    const int* ei_inter = (const int*)d_in[2];
    const float* head_Wt = (const float*)d_in[3];
    const float* head_Wi = (const float*)d_in[4];
    const float* head_Wr = (const float*)d_in[5];
    const float* head_b = (const float*)d_in[6];
    const float* blk_Wt = (const float*)d_in[7];
    const float* blk_Wi = (const float*)d_in[8];
    const float* blk_Wr = (const float*)d_in[9];
    const float* blk_b = (const float*)d_in[10];
    const float* last_Wt = (const float*)d_in[11];
    const float* last_Wi = (const float*)d_in[12];
    const float* last_Wr = (const float*)d_in[13];
    const float* last_b = (const float*)d_in[14];
    const float* last_proj = (const float*)d_in[15];

    const int N = in_sizes[0] / 6;
    const int Et = in_sizes[1] / 2;
    const int Ei = in_sizes[2] / 2;

    const int* temp_src = ei_temp;
    const int* temp_dst = ei_temp + Et;
    const int* int_src = ei_inter;
    const int* int_dst = ei_inter + Ei;

    const int shift = 7;                      // 128-node buckets
    const int NB = ((N - 1) >> shift) + 1;    // assumes N <= 131072

    char* p = (char*)d_ws;
    size_t off = 0;
    auto carve = [&](size_t bytes) {
        char* r = p + off;
        off = align256(off + bytes);
        return r;
    };
    // zero-init block: cnt_t, ovfn, gh contiguous -> ONE memset
    int* cnt_t = (int*)carve((size_t)N * 4);
    int* ovfn = (int*)carve(2 * 4);
    int* gh = (int*)carve((size_t)NB * 4);
    size_t zspan = (size_t)((char*)gh + (size_t)NB * 4 - (char*)cnt_t);
    int* ovf_t = (int*)carve((size_t)VO * 8);
    int* boff = (int*)carve((size_t)(NB + 1) * 4);
    int* cur = (int*)carve((size_t)NB * 4);
    int* rs = (int*)carve((size_t)(N + 1) * 4);
    float* x8 = (float*)carve((size_t)N * 8 * 4);
    float* bufA = (float*)carve((size_t)N * 32 * 4);
    float* bufD = (float*)carve((size_t)N * 32 * 4);
    float* agg = (float*)carve((size_t)N * 64 * 4);   // also holds agg8 [N,16]
    __half* h16 = (__half*)carve((size_t)N * 32 * 2); // fp16 gather staging
    int* ebuf = (int*)carve((size_t)Ei * 4);          // packed (src<<7 | dst&127)
    int* csr_i = (int*)carve((size_t)Ei * 4);         // dense
    const int Ct = 16;
    int* csr_t = (int*)carve((size_t)N * Ct * 4);
    (void)ws_size;

    const int B = 256;
    auto blocks = [&](long long work) { return (int)((work + B - 1) / B); };

    hipMemsetAsync(cnt_t, 0, zspan, stream);

    k_hist<<<256, B, 0, stream>>>(int_dst, Ei, gh, NB, shift);
    k_scan_b<<<1, 1024, 0, stream>>>(gh, NB, boff, cur);
    k_scatter<<<(int)((Ei + SCAT_SPAN - 1) / SCAT_SPAN), SCAT_THR, 0, stream>>>(
        int_src, int_dst, Ei, shift, NB, cur, ebuf);
    k_fill3<<<NB, B, 0, stream>>>(ebuf, boff, NB, rs, csr_i, N);
    k_fill2<<<blocks(Et), B, 0, stream>>>(temp_src, temp_dst, Et, cnt_t, csr_t, Ct, ovf_t, &ovfn[1]);
    k_pad_x<<<blocks((long long)N * 8), B, 0, stream>>>(x_stroke, x8, N);

    // wave-split GEMM grids
    const int gw2 = 2 * ((N + 63) >> 6);              // 2 waves per 64 nodes
    const int gblocks2 = ((gw2 << 6) + B - 1) / B;
    const int gw4 = 4 * ((N + 63) >> 6);              // 4 waves per 64 nodes
    const int gblocks4 = ((gw4 << 6) + B - 1) / B;
    // group-per-node gather grid: 8 nodes per wave
    const int gatherW = (N + 7) >> 3;
    const int gatherBlocks = (int)(((long long)gatherW * 64 + B - 1) / B);

    // head
    k_gather_head<<<blocks(N), B, 0, stream>>>(
        x8, csr_i, rs, csr_t, cnt_t, Ct, ovf_t, ovfn, agg, N);
    k_gemm_head<<<gblocks2, B, 0, stream>>>(agg, x8, head_Wt, head_Wi, head_Wr, head_b,
                                            bufA, h16, N);

    // 3 hidden residual blocks
    float* hin = bufA;
    float* hout = bufD;
    for (int i = 0; i < 3; ++i) {
        k_gather32<<<gatherBlocks, B, 0, stream>>>(
            h16, hin, csr_i, rs, csr_t, cnt_t, Ct, ovf_t, ovfn, agg, N);
        k_gemm_blk<<<gblocks2, B, 0, stream>>>(
            agg, hin, blk_Wt + (size_t)i * 32 * 32, blk_Wi + (size_t)i * 32 * 32,
            blk_Wr + (size_t)i * 32 * 32, blk_b + (size_t)i * 32, hout, h16, N);
        float* t = hin; hin = hout; hout = t;
    }

    // last
    k_gather32<<<gatherBlocks, B, 0, stream>>>(
        h16, hin, csr_i, rs, csr_t, cnt_t, Ct, ovf_t, ovfn, agg, N);
    k_gemm_last<<<gblocks4, B, 0, stream>>>(agg, hin, last_Wt, last_Wi, last_Wr, last_b,
                                            last_proj, (float*)d_out, N);
}